// Round 1
// baseline (547.051 us; speedup 1.0000x reference)
//
#include <hip/hip_runtime.h>
#include <hip/hip_bf16.h>

typedef __bf16 bf16;
typedef bf16 bf16x8 __attribute__((ext_vector_type(8)));
typedef float f32x4 __attribute__((ext_vector_type(4)));

#define HID 1024
#define NHEADS 16
#define HD 64
#define SEQ 4096
#define NKV 4
#define KVB 1024
#define ATT_SCALE 0.125f

// ---------------------------------------------------------------------------
// GEMM: C[M,N] = A[M,K] @ B[K,N]; A fp32 or bf16 (template), B fp32,
// C bf16 or fp32. MFMA 16x16x32 bf16. Tile 128x128, BK=32, 256 thr (2x2 waves
// of 64x64 each). fp32 inputs are converted to bf16 while staging to LDS.
// ---------------------------------------------------------------------------
template <typename AT, typename CT>
__global__ __launch_bounds__(256)
void gemm_kernel(const AT* __restrict__ A, const float* __restrict__ B,
                 CT* __restrict__ C, int M, int N, int K)
{
  // pad rows to 40 shorts (80B): keeps 16B alignment for b128, r/r+8 only
  // 2-way bank alias (free per m136)
  __shared__ bf16 As[128][40];
  __shared__ bf16 Bts[128][40];   // B transposed: Bts[n][k]

  const int t    = threadIdx.x;
  const int lane = t & 63;
  const int w    = t >> 6;
  const int wm   = (w & 1) * 64;
  const int wn   = (w >> 1) * 64;
  const int m0   = blockIdx.y * 128;
  const int n0   = blockIdx.x * 128;

  f32x4 acc[4][4] = {};

  const int arow = t >> 1;        // 0..127
  const int acol = (t & 1) * 16;  // 0,16
  const int brow = t >> 3;        // 0..31
  const int bcol = (t & 7) * 16;  // 0..112

  const int fr = lane & 15;
  const int fk = (lane >> 4) * 8;

  for (int k0 = 0; k0 < K; k0 += 32) {
    __syncthreads();
    // ---- stage A tile (128 x 32) ----
    {
      const AT* src = A + (size_t)(m0 + arow) * K + k0 + acol;
      bf16 tmp[16];
      if constexpr (sizeof(AT) == 4) {
        const float4* s4 = (const float4*)src;
        #pragma unroll
        for (int i = 0; i < 4; ++i) {
          float4 v = s4[i];
          tmp[i*4+0] = (bf16)v.x; tmp[i*4+1] = (bf16)v.y;
          tmp[i*4+2] = (bf16)v.z; tmp[i*4+3] = (bf16)v.w;
        }
      } else {
        const bf16x8* s8 = (const bf16x8*)src;
        *(bf16x8*)&tmp[0] = s8[0];
        *(bf16x8*)&tmp[8] = s8[1];
      }
      *(bf16x8*)&As[arow][acol]     = *(bf16x8*)&tmp[0];
      *(bf16x8*)&As[arow][acol + 8] = *(bf16x8*)&tmp[8];
    }
    // ---- stage B tile (32 x 128), transposed on store ----
    {
      const float* src = B + (size_t)(k0 + brow) * N + n0 + bcol;
      const float4* s4 = (const float4*)src;
      #pragma unroll
      for (int i = 0; i < 4; ++i) {
        float4 v = s4[i];
        Bts[bcol + i*4 + 0][brow] = (bf16)v.x;
        Bts[bcol + i*4 + 1][brow] = (bf16)v.y;
        Bts[bcol + i*4 + 2][brow] = (bf16)v.z;
        Bts[bcol + i*4 + 3][brow] = (bf16)v.w;
      }
    }
    __syncthreads();

    bf16x8 af[4], bg[4];
    #pragma unroll
    for (int i = 0; i < 4; ++i)
      af[i] = *(const bf16x8*)&As[wm + i*16 + fr][fk];
    #pragma unroll
    for (int i = 0; i < 4; ++i)
      bg[i] = *(const bf16x8*)&Bts[wn + i*16 + fr][fk];
    #pragma unroll
    for (int mi = 0; mi < 4; ++mi)
      #pragma unroll
      for (int ni = 0; ni < 4; ++ni)
        acc[mi][ni] = __builtin_amdgcn_mfma_f32_16x16x32_bf16(
            af[mi], bg[ni], acc[mi][ni], 0, 0, 0);
  }

  // epilogue: C/D layout col=lane&15, row=(lane>>4)*4+reg
  const int rq = (lane >> 4) * 4;
  #pragma unroll
  for (int mi = 0; mi < 4; ++mi)
    #pragma unroll
    for (int ni = 0; ni < 4; ++ni)
      #pragma unroll
      for (int r = 0; r < 4; ++r) {
        int row = m0 + wm + mi*16 + rq + r;
        int c   = n0 + wn + ni*16 + fr;
        float v = acc[mi][ni][r];
        if constexpr (sizeof(CT) == 2) C[(size_t)row * N + c] = (bf16)v;
        else                           C[(size_t)row * N + c] = v;
      }
}

// ---------------------------------------------------------------------------
// Ring attention. One workgroup per (64 Q rows, head). 4 waves; wave w owns
// Q rows [w*16, w*16+16). Per KV block of 1024 keys: online-softmax with
// LOCAL max (reset each block), folded additively into (num, den) — this
// reproduces the reference's per-block local-max semantics exactly.
// ---------------------------------------------------------------------------
__global__ __launch_bounds__(256)
void attn_kernel(const bf16* __restrict__ Q, const bf16* __restrict__ K,
                 const bf16* __restrict__ V, bf16* __restrict__ O)
{
  __shared__ bf16 Ks [64][72];  // [key][d]
  __shared__ bf16 Vts[64][72];  // [d][key]  (transposed for B-frags)
  __shared__ bf16 Ps [64][72];  // [qrow][key] per-wave 16-row slabs

  const int t    = threadIdx.x;
  const int lane = t & 63;
  const int w    = t >> 6;
  const int h    = blockIdx.y;
  const int q0   = blockIdx.x * 64;

  const int fr   = lane & 15;
  const int quad = lane >> 4;
  const int fk   = quad * 8;

  // Q fragments: A-layout, rows q0+w*16+fr, k-slices d 0..31 / 32..63
  bf16x8 aq0, aq1;
  {
    const bf16* qp = Q + (size_t)(q0 + w*16 + fr) * HID + h * HD;
    aq0 = *(const bf16x8*)(qp + fk);
    aq1 = *(const bf16x8*)(qp + 32 + fk);
  }

  f32x4 accN[4] = {};
  float den[4] = {0.f, 0.f, 0.f, 0.f};

  const int skey = t >> 2;         // 0..63
  const int sd   = (t & 3) * 16;   // 0,16,32,48

  for (int kb = 0; kb < NKV; ++kb) {
    f32x4 accO[4] = {};
    float mrow[4] = {-1e30f, -1e30f, -1e30f, -1e30f};
    float lrow[4] = {0.f, 0.f, 0.f, 0.f};

    for (int kt = 0; kt < KVB / 64; ++kt) {
      const int key0 = kb * KVB + kt * 64;
      __syncthreads();
      {
        const bf16* kp = K + (size_t)(key0 + skey) * HID + h * HD + sd;
        bf16x8 k0v = *(const bf16x8*)kp;
        bf16x8 k1v = *(const bf16x8*)(kp + 8);
        *(bf16x8*)&Ks[skey][sd]     = k0v;
        *(bf16x8*)&Ks[skey][sd + 8] = k1v;
        const bf16* vp = V + (size_t)(key0 + skey) * HID + h * HD + sd;
        bf16x8 v0 = *(const bf16x8*)vp;
        bf16x8 v1 = *(const bf16x8*)(vp + 8);
        #pragma unroll
        for (int j = 0; j < 8; ++j) Vts[sd + j][skey]     = v0[j];
        #pragma unroll
        for (int j = 0; j < 8; ++j) Vts[sd + 8 + j][skey] = v1[j];
      }
      __syncthreads();

      // S = scale * Q K^T  (16 q-rows x 64 keys per wave)
      f32x4 s[4];
      #pragma unroll
      for (int nt = 0; nt < 4; ++nt) {
        bf16x8 b0 = *(const bf16x8*)&Ks[nt*16 + fr][fk];
        bf16x8 b1 = *(const bf16x8*)&Ks[nt*16 + fr][32 + fk];
        f32x4 z = {};
        z = __builtin_amdgcn_mfma_f32_16x16x32_bf16(aq0, b0, z, 0, 0, 0);
        z = __builtin_amdgcn_mfma_f32_16x16x32_bf16(aq1, b1, z, 0, 0, 0);
        s[nt] = z;
      }

      // per-row local max update (rows = quad*4+r); 16-lane xor reduce
      float mnew[4], alpha[4];
      #pragma unroll
      for (int r = 0; r < 4; ++r) {
        float mx = -1e30f;
        #pragma unroll
        for (int nt = 0; nt < 4; ++nt) {
          s[nt][r] *= ATT_SCALE;
          mx = fmaxf(mx, s[nt][r]);
        }
        mx = fmaxf(mx, __shfl_xor(mx, 1));
        mx = fmaxf(mx, __shfl_xor(mx, 2));
        mx = fmaxf(mx, __shfl_xor(mx, 4));
        mx = fmaxf(mx, __shfl_xor(mx, 8));
        mnew[r]  = fmaxf(mrow[r], mx);
        alpha[r] = __expf(mrow[r] - mnew[r]);
        mrow[r]  = mnew[r];
      }

      // P = exp(s - m); write bf16 into per-wave Ps slab; row sums
      #pragma unroll
      for (int r = 0; r < 4; ++r) {
        float sum = 0.f;
        #pragma unroll
        for (int nt = 0; nt < 4; ++nt) {
          float p = __expf(s[nt][r] - mnew[r]);
          sum += p;
          Ps[w*16 + quad*4 + r][nt*16 + fr] = (bf16)p;
        }
        sum += __shfl_xor(sum, 1);
        sum += __shfl_xor(sum, 2);
        sum += __shfl_xor(sum, 4);
        sum += __shfl_xor(sum, 8);
        lrow[r] = lrow[r] * alpha[r] + sum;
        #pragma unroll
        for (int nt = 0; nt < 4; ++nt) accO[nt][r] *= alpha[r];
      }

      // O += P @ V (Ps slab is wave-private: no barrier needed)
      bf16x8 ap0 = *(const bf16x8*)&Ps[w*16 + fr][fk];
      bf16x8 ap1 = *(const bf16x8*)&Ps[w*16 + fr][32 + fk];
      #pragma unroll
      for (int nt = 0; nt < 4; ++nt) {
        bf16x8 b0 = *(const bf16x8*)&Vts[nt*16 + fr][fk];
        bf16x8 b1 = *(const bf16x8*)&Vts[nt*16 + fr][32 + fk];
        accO[nt] = __builtin_amdgcn_mfma_f32_16x16x32_bf16(ap0, b0, accO[nt], 0, 0, 0);
        accO[nt] = __builtin_amdgcn_mfma_f32_16x16x32_bf16(ap1, b1, accO[nt], 0, 0, 0);
      }
    }

    // fold block into global accumulators (block-local max reference)
    #pragma unroll
    for (int nt = 0; nt < 4; ++nt)
      #pragma unroll
      for (int r = 0; r < 4; ++r) accN[nt][r] += accO[nt][r];
    #pragma unroll
    for (int r = 0; r < 4; ++r) den[r] += lrow[r];
  }

  // out = num / den, bf16 [S][HID]
  #pragma unroll
  for (int r = 0; r < 4; ++r) {
    float inv = 1.0f / den[r];
    int row = q0 + w*16 + quad*4 + r;
    #pragma unroll
    for (int nt = 0; nt < 4; ++nt)
      O[(size_t)row * HID + h*HD + nt*16 + fr] = (bf16)(accN[nt][r] * inv);
  }
}

extern "C" void kernel_launch(void* const* d_in, const int* in_sizes, int n_in,
                              void* d_out, int out_size, void* d_ws, size_t ws_size,
                              hipStream_t stream)
{
  const float* X  = (const float*)d_in[0];
  const float* Wq = (const float*)d_in[1];
  const float* Wk = (const float*)d_in[2];
  const float* Wv = (const float*)d_in[3];
  const float* Wo = (const float*)d_in[4];
  float* out = (float*)d_out;

  bf16* Qg = (bf16*)d_ws;                      // [SEQ][HID] bf16, 8 MB
  bf16* Kg = Qg + (size_t)SEQ * HID;           // 8 MB
  bf16* Vg = Kg + (size_t)SEQ * HID;           // 8 MB
  bf16* Og = Vg + (size_t)SEQ * HID;           // 8 MB (attention output)

  dim3 gg(HID / 128, SEQ / 128);
  gemm_kernel<float, bf16><<<gg, 256, 0, stream>>>(X, Wq, Qg, SEQ, HID, HID);
  gemm_kernel<float, bf16><<<gg, 256, 0, stream>>>(X, Wk, Kg, SEQ, HID, HID);
  gemm_kernel<float, bf16><<<gg, 256, 0, stream>>>(X, Wv, Vg, SEQ, HID, HID);

  attn_kernel<<<dim3(SEQ / 64, NHEADS), 256, 0, stream>>>(Qg, Kg, Vg, Og);

  gemm_kernel<bf16, float><<<gg, 256, 0, stream>>>(Og, Wo, out, SEQ, HID, HID);
}

// Round 2
// 337.980 us; speedup vs baseline: 1.6186x; 1.6186x over previous
//
#include <hip/hip_runtime.h>
#include <hip/hip_bf16.h>

typedef __bf16 bf16;
typedef bf16 bf16x4 __attribute__((ext_vector_type(4)));
typedef bf16 bf16x8 __attribute__((ext_vector_type(8)));
typedef float f32x4 __attribute__((ext_vector_type(4)));

#define HID 1024
#define NHEADS 16
#define HD 64
#define SEQ 4096

__device__ __forceinline__ void gll16(const void* g, void* l) {
  __builtin_amdgcn_global_load_lds(
      (const __attribute__((address_space(1))) void*)g,
      (__attribute__((address_space(3))) void*)l, 16, 0, 0);
}

// ---------------------------------------------------------------------------
// Prep: z=0 convert X fp32->bf16; z=1..4 transpose+convert W -> Wt[out][in],
// folding attention scale (0.125, exact in bf16) into Wq.
// ---------------------------------------------------------------------------
__global__ __launch_bounds__(256)
void prep_kernel(const float* __restrict__ X,
                 const float* __restrict__ Wq, const float* __restrict__ Wk,
                 const float* __restrict__ Wv, const float* __restrict__ Wo,
                 bf16* __restrict__ Xb, bf16* __restrict__ Wt)
{
  const int z = blockIdx.z, t = threadIdx.x, bx = blockIdx.x;
  if (z == 0) {
    const float4* src = (const float4*)X;
    const int gid = bx * 256 + t;
    #pragma unroll
    for (int i = 0; i < 16; ++i) {
      float4 v = src[gid + i * 65536];
      bf16x4 o = {(bf16)v.x, (bf16)v.y, (bf16)v.z, (bf16)v.w};
      *(bf16x4*)&Xb[(size_t)(gid + i * 65536) * 4] = o;
    }
  } else {
    const float* W = (z == 1) ? Wq : (z == 2) ? Wk : (z == 3) ? Wv : Wo;
    bf16* dst = Wt + (size_t)(z - 1) * HID * HID;
    const float scale = (z == 1) ? 0.125f : 1.0f;
    __shared__ bf16 T[64][68];
    const int tr = (bx >> 4) * 64, tc = (bx & 15) * 64;
    #pragma unroll
    for (int p = 0; p < 4; ++p) {
      int row = (t >> 4) + p * 16;
      float4 v = *(const float4*)&W[(size_t)(tr + row) * HID + tc + (t & 15) * 4];
      T[row][(t & 15) * 4 + 0] = (bf16)(v.x * scale);
      T[row][(t & 15) * 4 + 1] = (bf16)(v.y * scale);
      T[row][(t & 15) * 4 + 2] = (bf16)(v.z * scale);
      T[row][(t & 15) * 4 + 3] = (bf16)(v.w * scale);
    }
    __syncthreads();
    #pragma unroll
    for (int p = 0; p < 4; ++p) {
      int rp = (t >> 4) + p * 16;   // n-local (out dim)
      int cb = (t & 15) * 4;        // k-local base (in dim)
      bf16x4 o = {T[cb + 0][rp], T[cb + 1][rp], T[cb + 2][rp], T[cb + 3][rp]};
      *(bf16x4*)&dst[(size_t)(tc + rp) * HID + tr + cb] = o;
    }
  }
}

// ---------------------------------------------------------------------------
// QKV GEMM: C = Xb[M,K] @ Wt[z][N,K]^T; z=0->Qg, 1->Kg, 2->Vt (transposed
// epilogue through LDS, writes Vt[hid][seq] coalesced). 128x128 tile, BK=64,
// global_load_lds staging, 2x2 waves of 64x64.
// ---------------------------------------------------------------------------
__global__ __launch_bounds__(256)
void qkv_gemm(const bf16* __restrict__ A, const bf16* __restrict__ Wt,
              bf16* __restrict__ Qg, bf16* __restrict__ Kg,
              bf16* __restrict__ Vt)
{
  __shared__ bf16 sbuf[16384];
  bf16* As = sbuf;
  bf16* Bs = sbuf + 8192;

  const int t = threadIdx.x, lane = t & 63, w = t >> 6;
  const int z = blockIdx.z;
  const int n0 = blockIdx.x * 128, m0 = blockIdx.y * 128;
  const bf16* Bt = Wt + (size_t)z * HID * HID;
  const int wm = (w & 1) * 64, wn = (w >> 1) * 64;
  const int fr = lane & 15, quad = lane >> 4;

  f32x4 acc[4][4] = {};

  const int srow = lane >> 3;        // 0..7
  const int scol = (lane & 7) * 8;   // shorts
  const bf16* ga = A  + (size_t)(m0 + w * 32 + srow) * HID + scol;
  const bf16* gb = Bt + (size_t)(n0 + w * 32 + srow) * HID + scol;

  for (int k0 = 0; k0 < HID; k0 += 64) {
    __syncthreads();
    #pragma unroll
    for (int c = 0; c < 4; ++c) {
      gll16(ga + (size_t)(c * 8) * HID + k0, As + (w * 32 + c * 8) * 64);
      gll16(gb + (size_t)(c * 8) * HID + k0, Bs + (w * 32 + c * 8) * 64);
    }
    __syncthreads();
    #pragma unroll
    for (int ks = 0; ks < 2; ++ks) {
      bf16x8 af[4], bg[4];
      #pragma unroll
      for (int i = 0; i < 4; ++i)
        af[i] = *(const bf16x8*)&As[(wm + i * 16 + fr) * 64 + ks * 32 + quad * 8];
      #pragma unroll
      for (int i = 0; i < 4; ++i)
        bg[i] = *(const bf16x8*)&Bs[(wn + i * 16 + fr) * 64 + ks * 32 + quad * 8];
      #pragma unroll
      for (int mi = 0; mi < 4; ++mi)
        #pragma unroll
        for (int ni = 0; ni < 4; ++ni)
          acc[mi][ni] = __builtin_amdgcn_mfma_f32_16x16x32_bf16(
              af[mi], bg[ni], acc[mi][ni], 0, 0, 0);
    }
  }

  if (z < 2) {
    bf16* C = z ? Kg : Qg;
    #pragma unroll
    for (int mi = 0; mi < 4; ++mi)
      #pragma unroll
      for (int ni = 0; ni < 4; ++ni)
        #pragma unroll
        for (int r = 0; r < 4; ++r)
          C[(size_t)(m0 + wm + mi * 16 + quad * 4 + r) * HID +
            n0 + wn + ni * 16 + fr] = (bf16)acc[mi][ni][r];
  } else {
    __syncthreads();
    #pragma unroll
    for (int mi = 0; mi < 4; ++mi)
      #pragma unroll
      for (int ni = 0; ni < 4; ++ni)
        #pragma unroll
        for (int r = 0; r < 4; ++r)
          sbuf[(wn + ni * 16 + fr) * 128 + wm + mi * 16 + quad * 4 + r] =
              (bf16)acc[mi][ni][r];
    __syncthreads();
    const int row = t >> 1, cb = (t & 1) * 64;
    #pragma unroll
    for (int j = 0; j < 8; ++j)
      *(bf16x8*)&Vt[(size_t)(n0 + row) * SEQ + m0 + cb + j * 8] =
          *(const bf16x8*)&sbuf[row * 128 + cb + j * 8];
  }
}

// ---------------------------------------------------------------------------
// O-projection: out = Og[M,K] @ Wto[N,K]^T, fp32 out. Same structure.
// ---------------------------------------------------------------------------
__global__ __launch_bounds__(256)
void oproj_gemm(const bf16* __restrict__ A, const bf16* __restrict__ Bt,
                float* __restrict__ C)
{
  __shared__ bf16 sbuf[16384];
  bf16* As = sbuf;
  bf16* Bs = sbuf + 8192;

  const int t = threadIdx.x, lane = t & 63, w = t >> 6;
  const int n0 = blockIdx.x * 128, m0 = blockIdx.y * 128;
  const int wm = (w & 1) * 64, wn = (w >> 1) * 64;
  const int fr = lane & 15, quad = lane >> 4;

  f32x4 acc[4][4] = {};

  const int srow = lane >> 3;
  const int scol = (lane & 7) * 8;
  const bf16* ga = A  + (size_t)(m0 + w * 32 + srow) * HID + scol;
  const bf16* gb = Bt + (size_t)(n0 + w * 32 + srow) * HID + scol;

  for (int k0 = 0; k0 < HID; k0 += 64) {
    __syncthreads();
    #pragma unroll
    for (int c = 0; c < 4; ++c) {
      gll16(ga + (size_t)(c * 8) * HID + k0, As + (w * 32 + c * 8) * 64);
      gll16(gb + (size_t)(c * 8) * HID + k0, Bs + (w * 32 + c * 8) * 64);
    }
    __syncthreads();
    #pragma unroll
    for (int ks = 0; ks < 2; ++ks) {
      bf16x8 af[4], bg[4];
      #pragma unroll
      for (int i = 0; i < 4; ++i)
        af[i] = *(const bf16x8*)&As[(wm + i * 16 + fr) * 64 + ks * 32 + quad * 8];
      #pragma unroll
      for (int i = 0; i < 4; ++i)
        bg[i] = *(const bf16x8*)&Bs[(wn + i * 16 + fr) * 64 + ks * 32 + quad * 8];
      #pragma unroll
      for (int mi = 0; mi < 4; ++mi)
        #pragma unroll
        for (int ni = 0; ni < 4; ++ni)
          acc[mi][ni] = __builtin_amdgcn_mfma_f32_16x16x32_bf16(
              af[mi], bg[ni], acc[mi][ni], 0, 0, 0);
    }
  }

  #pragma unroll
  for (int mi = 0; mi < 4; ++mi)
    #pragma unroll
    for (int ni = 0; ni < 4; ++ni)
      #pragma unroll
      for (int r = 0; r < 4; ++r)
        C[(size_t)(m0 + wm + mi * 16 + quad * 4 + r) * HID +
          n0 + wn + ni * 16 + fr] = acc[mi][ni][r];
}

// ---------------------------------------------------------------------------
// Attention v2: S^T = K.Q^T (both operands natural layout; Q in registers).
// Each lane owns one q-row (col=fr) -> 2-shuffle reductions, scalar m/l.
// P stored to wave-private LDS in [q][key] layout (b128-readable B-frag).
// O^T = V^T . P^T with V^T staged from global Vt via global_load_lds.
// Per-1024-block local max, additive (num,den) across blocks == reference.
// ---------------------------------------------------------------------------
__global__ __launch_bounds__(256)
void attn2(const bf16* __restrict__ Q, const bf16* __restrict__ K,
           const bf16* __restrict__ Vt, bf16* __restrict__ O)
{
  __shared__ bf16 Ks[64 * 64];
  __shared__ bf16 Vs[64 * 64];
  __shared__ bf16 Ps[4][16 * 72];

  const int t = threadIdx.x, lane = t & 63, w = t >> 6;
  const int h = blockIdx.y, q0 = blockIdx.x * 64;
  const int fr = lane & 15, quad = lane >> 4;
  const int qrow = q0 + w * 16 + fr;

  const bf16x8 bq0 = *(const bf16x8*)&Q[(size_t)qrow * HID + h * 64 + quad * 8];
  const bf16x8 bq1 = *(const bf16x8*)&Q[(size_t)qrow * HID + h * 64 + 32 + quad * 8];

  const int srow = lane >> 3, scol = (lane & 7) * 8;
  const bf16* gk = K  + (size_t)(w * 16 + srow) * HID + h * 64 + scol;
  const bf16* gv = Vt + (size_t)(h * 64 + w * 16 + srow) * SEQ + scol;

  f32x4 accN[4] = {};
  float den = 0.f;

  for (int kb = 0; kb < 4; ++kb) {
    f32x4 accO[4] = {};
    float m_i = -1e30f, l_i = 0.f;
    for (int kt = 0; kt < 16; ++kt) {
      const int key0 = kb * 1024 + kt * 64;
      __syncthreads();
      #pragma unroll
      for (int c = 0; c < 2; ++c) {
        gll16(gk + (size_t)(key0 + c * 8) * HID, Ks + (w * 16 + c * 8) * 64);
        gll16(gv + (size_t)(c * 8) * SEQ + key0, Vs + (w * 16 + c * 8) * 64);
      }
      __syncthreads();

      // S^T tile: D[key][q], A = K rows from LDS, B = Q rows from regs
      f32x4 s[4];
      #pragma unroll
      for (int mt = 0; mt < 4; ++mt) {
        bf16x8 a0 = *(const bf16x8*)&Ks[(mt * 16 + fr) * 64 + quad * 8];
        bf16x8 a1 = *(const bf16x8*)&Ks[(mt * 16 + fr) * 64 + 32 + quad * 8];
        f32x4 zz = {};
        zz = __builtin_amdgcn_mfma_f32_16x16x32_bf16(a0, bq0, zz, 0, 0, 0);
        zz = __builtin_amdgcn_mfma_f32_16x16x32_bf16(a1, bq1, zz, 0, 0, 0);
        s[mt] = zz;
      }

      // online max for this lane's single q-row (keys: mt*16+quad*4+r)
      float mx = -1e30f;
      #pragma unroll
      for (int mt = 0; mt < 4; ++mt)
        #pragma unroll
        for (int r = 0; r < 4; ++r) mx = fmaxf(mx, s[mt][r]);
      mx = fmaxf(mx, __shfl_xor(mx, 16));
      mx = fmaxf(mx, __shfl_xor(mx, 32));
      const float mnew = fmaxf(m_i, mx);
      const float alpha = __expf(m_i - mnew);
      m_i = mnew;

      float sum = 0.f;
      #pragma unroll
      for (int mt = 0; mt < 4; ++mt)
        #pragma unroll
        for (int r = 0; r < 4; ++r) {
          float p = __expf(s[mt][r] - mnew);
          sum += p;
          Ps[w][fr * 72 + mt * 16 + quad * 4 + r] = (bf16)p;
        }
      sum += __shfl_xor(sum, 16);
      sum += __shfl_xor(sum, 32);
      l_i = l_i * alpha + sum;
      #pragma unroll
      for (int dt = 0; dt < 4; ++dt)
        #pragma unroll
        for (int r = 0; r < 4; ++r) accO[dt][r] *= alpha;

      // O^T += V^T . P^T : A = V^T rows (d), B = P rows (q)
      #pragma unroll
      for (int ks = 0; ks < 2; ++ks) {
        bf16x8 bp = *(const bf16x8*)&Ps[w][fr * 72 + ks * 32 + quad * 8];
        #pragma unroll
        for (int dt = 0; dt < 4; ++dt) {
          bf16x8 av = *(const bf16x8*)&Vs[(dt * 16 + fr) * 64 + ks * 32 + quad * 8];
          accO[dt] = __builtin_amdgcn_mfma_f32_16x16x32_bf16(av, bp, accO[dt], 0, 0, 0);
        }
      }
    }
    #pragma unroll
    for (int dt = 0; dt < 4; ++dt)
      #pragma unroll
      for (int r = 0; r < 4; ++r) accN[dt][r] += accO[dt][r];
    den += l_i;
  }

  const float inv = 1.0f / den;
  #pragma unroll
  for (int dt = 0; dt < 4; ++dt)
    #pragma unroll
    for (int r = 0; r < 4; ++r)
      O[(size_t)qrow * HID + h * 64 + dt * 16 + quad * 4 + r] =
          (bf16)(accN[dt][r] * inv);
}

extern "C" void kernel_launch(void* const* d_in, const int* in_sizes, int n_in,
                              void* d_out, int out_size, void* d_ws, size_t ws_size,
                              hipStream_t stream)
{
  const float* X  = (const float*)d_in[0];
  const float* Wq = (const float*)d_in[1];
  const float* Wk = (const float*)d_in[2];
  const float* Wv = (const float*)d_in[3];
  const float* Wo = (const float*)d_in[4];
  float* out = (float*)d_out;

  const size_t MB = 1024 * 1024;
  bf16* Xb  = (bf16*)d_ws;                       // 8 MB
  bf16* Wt  = (bf16*)((char*)d_ws + 8  * MB);    // 4 x 2 MB
  bf16* Qg  = (bf16*)((char*)d_ws + 16 * MB);    // 8 MB
  bf16* Kg  = (bf16*)((char*)d_ws + 24 * MB);    // 8 MB
  bf16* Vtg = (bf16*)((char*)d_ws + 32 * MB);    // 8 MB, [hid][seq]
  bf16* Og  = (bf16*)((char*)d_ws + 40 * MB);    // 8 MB

  prep_kernel<<<dim3(256, 1, 5), 256, 0, stream>>>(X, Wq, Wk, Wv, Wo, Xb, Wt);
  qkv_gemm<<<dim3(HID / 128, SEQ / 128, 3), 256, 0, stream>>>(Xb, Wt, Qg, Kg, Vtg);
  attn2<<<dim3(SEQ / 64, NHEADS), 256, 0, stream>>>(Qg, Kg, Vtg, Og);
  oproj_gemm<<<dim3(HID / 128, SEQ / 128), 256, 0, stream>>>(
      Og, Wt + (size_t)3 * HID * HID, out);
}

// Round 3
// 274.905 us; speedup vs baseline: 1.9900x; 1.2294x over previous
//
#include <hip/hip_runtime.h>
#include <hip/hip_bf16.h>

typedef __bf16 bf16;
typedef bf16 bf16x2 __attribute__((ext_vector_type(2)));
typedef bf16 bf16x4 __attribute__((ext_vector_type(4)));
typedef bf16 bf16x8 __attribute__((ext_vector_type(8)));
typedef float f32x4 __attribute__((ext_vector_type(4)));

#define HID 1024
#define NHEADS 16
#define HD 64
#define SEQ 4096

__device__ __forceinline__ void gll16(const void* g, void* l) {
  __builtin_amdgcn_global_load_lds(
      (const __attribute__((address_space(1))) void*)g,
      (__attribute__((address_space(3))) void*)l, 16, 0, 0);
}

// ---------------------------------------------------------------------------
// Prep: z=0 convert X fp32->bf16; z=1..4 transpose+convert W -> Wt[out][in],
// folding attention scale (0.125, exact) into Wq.
// ---------------------------------------------------------------------------
__global__ __launch_bounds__(256)
void prep_kernel(const float* __restrict__ X,
                 const float* __restrict__ Wq, const float* __restrict__ Wk,
                 const float* __restrict__ Wv, const float* __restrict__ Wo,
                 bf16* __restrict__ Xb, bf16* __restrict__ Wt)
{
  const int z = blockIdx.z, t = threadIdx.x, bx = blockIdx.x;
  if (z == 0) {
    const float4* src = (const float4*)X;
    const int gid = bx * 256 + t;
    #pragma unroll
    for (int i = 0; i < 16; ++i) {
      float4 v = src[gid + i * 65536];
      bf16x4 o = {(bf16)v.x, (bf16)v.y, (bf16)v.z, (bf16)v.w};
      *(bf16x4*)&Xb[(size_t)(gid + i * 65536) * 4] = o;
    }
  } else {
    const float* W = (z == 1) ? Wq : (z == 2) ? Wk : (z == 3) ? Wv : Wo;
    bf16* dst = Wt + (size_t)(z - 1) * HID * HID;
    const float scale = (z == 1) ? 0.125f : 1.0f;
    __shared__ bf16 T[64][68];
    const int tr = (bx >> 4) * 64, tc = (bx & 15) * 64;
    #pragma unroll
    for (int p = 0; p < 4; ++p) {
      int row = (t >> 4) + p * 16;
      float4 v = *(const float4*)&W[(size_t)(tr + row) * HID + tc + (t & 15) * 4];
      T[row][(t & 15) * 4 + 0] = (bf16)(v.x * scale);
      T[row][(t & 15) * 4 + 1] = (bf16)(v.y * scale);
      T[row][(t & 15) * 4 + 2] = (bf16)(v.z * scale);
      T[row][(t & 15) * 4 + 3] = (bf16)(v.w * scale);
    }
    __syncthreads();
    #pragma unroll
    for (int p = 0; p < 4; ++p) {
      int rp = (t >> 4) + p * 16;
      int cb = (t & 15) * 4;
      bf16x4 o = {T[cb + 0][rp], T[cb + 1][rp], T[cb + 2][rp], T[cb + 3][rp]};
      *(bf16x4*)&dst[(size_t)(tc + rp) * HID + tr + cb] = o;
    }
  }
}

// ---------------------------------------------------------------------------
// QKV GEMM: C = Xb[M,K] @ Wt[z][N,K]^T. 128x128 tile, BK=64, global_load_lds
// staging with chunk-rotation swizzle (row k chunk c -> slot k*8+((c+k)&7))
// so column-of-rows frag reads spread over all 32 banks.
// z=2 writes V transposed (Vt[hid][seq]) via swizzled LDS transpose.
// ---------------------------------------------------------------------------
__global__ __launch_bounds__(256)
void qkv_gemm(const bf16* __restrict__ A, const bf16* __restrict__ Wt,
              bf16* __restrict__ Qg, bf16* __restrict__ Kg,
              bf16* __restrict__ Vt)
{
  __shared__ bf16 sbuf[16384];
  bf16* As = sbuf;
  bf16* Bs = sbuf + 8192;

  const int t = threadIdx.x, lane = t & 63, w = t >> 6;
  const int z = blockIdx.z;
  const int n0 = blockIdx.x * 128, m0 = blockIdx.y * 128;
  const bf16* Bt = Wt + (size_t)z * HID * HID;
  const int wm = (w & 1) * 64, wn = (w >> 1) * 64;
  const int fr = lane & 15, quad = lane >> 4;

  f32x4 acc[4][4] = {};

  const int sr = lane >> 3;              // 0..7
  const int sc = ((lane & 7) - sr) & 7;  // rotated chunk
  const bf16* ga = A  + (size_t)(m0 + w * 32 + sr) * HID + sc * 8;
  const bf16* gb = Bt + (size_t)(n0 + w * 32 + sr) * HID + sc * 8;

  for (int k0 = 0; k0 < HID; k0 += 64) {
    __syncthreads();
    #pragma unroll
    for (int c = 0; c < 4; ++c) {
      gll16(ga + (size_t)(c * 8) * HID + k0, As + (w * 32 + c * 8) * 64);
      gll16(gb + (size_t)(c * 8) * HID + k0, Bs + (w * 32 + c * 8) * 64);
    }
    __syncthreads();
    #pragma unroll
    for (int ks = 0; ks < 2; ++ks) {
      bf16x8 af[4], bg[4];
      #pragma unroll
      for (int i = 0; i < 4; ++i)
        af[i] = *(const bf16x8*)&As[(wm + i * 16 + fr) * 64 +
                                    ((ks * 4 + quad + fr) & 7) * 8];
      #pragma unroll
      for (int i = 0; i < 4; ++i)
        bg[i] = *(const bf16x8*)&Bs[(wn + i * 16 + fr) * 64 +
                                    ((ks * 4 + quad + fr) & 7) * 8];
      #pragma unroll
      for (int mi = 0; mi < 4; ++mi)
        #pragma unroll
        for (int ni = 0; ni < 4; ++ni)
          acc[mi][ni] = __builtin_amdgcn_mfma_f32_16x16x32_bf16(
              af[mi], bg[ni], acc[mi][ni], 0, 0, 0);
    }
  }

  if (z < 2) {
    bf16* C = z ? Kg : Qg;
    #pragma unroll
    for (int mi = 0; mi < 4; ++mi)
      #pragma unroll
      for (int ni = 0; ni < 4; ++ni)
        #pragma unroll
        for (int r = 0; r < 4; ++r)
          C[(size_t)(m0 + wm + mi * 16 + quad * 4 + r) * HID +
            n0 + wn + ni * 16 + fr] = (bf16)acc[mi][ni][r];
  } else {
    __syncthreads();
    // swizzled transpose: col stored at (col + 8*(row&15)) & 127
    #pragma unroll
    for (int mi = 0; mi < 4; ++mi)
      #pragma unroll
      for (int ni = 0; ni < 4; ++ni)
        #pragma unroll
        for (int r = 0; r < 4; ++r) {
          int row = wn + ni * 16 + fr;
          int col = wm + mi * 16 + quad * 4 + r;
          int colS = (col + 8 * (row & 15)) & 127;
          sbuf[row * 128 + colS] = (bf16)acc[mi][ni][r];
        }
    __syncthreads();
    const int row = t >> 1, cb = (t & 1) * 64;
    #pragma unroll
    for (int j = 0; j < 8; ++j) {
      int c0 = (cb + j * 8 + 8 * (row & 15)) & 127;
      *(bf16x8*)&Vt[(size_t)(n0 + row) * SEQ + m0 + cb + j * 8] =
          *(const bf16x8*)&sbuf[row * 128 + c0];
    }
  }
}

// ---------------------------------------------------------------------------
// O-projection: out = Og[M,K] @ Wto[N,K]^T, fp32 out. Same swizzled staging.
// ---------------------------------------------------------------------------
__global__ __launch_bounds__(256)
void oproj_gemm(const bf16* __restrict__ A, const bf16* __restrict__ Bt,
                float* __restrict__ C)
{
  __shared__ bf16 sbuf[16384];
  bf16* As = sbuf;
  bf16* Bs = sbuf + 8192;

  const int t = threadIdx.x, lane = t & 63, w = t >> 6;
  const int n0 = blockIdx.x * 128, m0 = blockIdx.y * 128;
  const int wm = (w & 1) * 64, wn = (w >> 1) * 64;
  const int fr = lane & 15, quad = lane >> 4;

  f32x4 acc[4][4] = {};

  const int sr = lane >> 3;
  const int sc = ((lane & 7) - sr) & 7;
  const bf16* ga = A  + (size_t)(m0 + w * 32 + sr) * HID + sc * 8;
  const bf16* gb = Bt + (size_t)(n0 + w * 32 + sr) * HID + sc * 8;

  for (int k0 = 0; k0 < HID; k0 += 64) {
    __syncthreads();
    #pragma unroll
    for (int c = 0; c < 4; ++c) {
      gll16(ga + (size_t)(c * 8) * HID + k0, As + (w * 32 + c * 8) * 64);
      gll16(gb + (size_t)(c * 8) * HID + k0, Bs + (w * 32 + c * 8) * 64);
    }
    __syncthreads();
    #pragma unroll
    for (int ks = 0; ks < 2; ++ks) {
      bf16x8 af[4], bg[4];
      #pragma unroll
      for (int i = 0; i < 4; ++i)
        af[i] = *(const bf16x8*)&As[(wm + i * 16 + fr) * 64 +
                                    ((ks * 4 + quad + fr) & 7) * 8];
      #pragma unroll
      for (int i = 0; i < 4; ++i)
        bg[i] = *(const bf16x8*)&Bs[(wn + i * 16 + fr) * 64 +
                                    ((ks * 4 + quad + fr) & 7) * 8];
      #pragma unroll
      for (int mi = 0; mi < 4; ++mi)
        #pragma unroll
        for (int ni = 0; ni < 4; ++ni)
          acc[mi][ni] = __builtin_amdgcn_mfma_f32_16x16x32_bf16(
              af[mi], bg[ni], acc[mi][ni], 0, 0, 0);
    }
  }

  #pragma unroll
  for (int mi = 0; mi < 4; ++mi)
    #pragma unroll
    for (int ni = 0; ni < 4; ++ni)
      #pragma unroll
      for (int r = 0; r < 4; ++r)
        C[(size_t)(m0 + wm + mi * 16 + quad * 4 + r) * HID +
          n0 + wn + ni * 16 + fr] = acc[mi][ni][r];
}

// ---------------------------------------------------------------------------
// Attention v3: 32 q-rows/wave (wg = 128 q x 1 head), S^T = K.Q^T.
// K/V tiles double-buffered in LDS with chunk-rotation swizzle; one barrier
// per KV tile; P kept in wave-private swizzled LDS (bf16x4 writes).
// Per-1024-block local max via online rescale == reference semantics.
// ---------------------------------------------------------------------------
__global__ __launch_bounds__(256)
void attn3(const bf16* __restrict__ Q, const bf16* __restrict__ K,
           const bf16* __restrict__ Vt, bf16* __restrict__ O)
{
  __shared__ bf16 Ks[2][4096];
  __shared__ bf16 Vs[2][4096];
  __shared__ bf16 Ps[4][2048];

  const int t = threadIdx.x, lane = t & 63, w = t >> 6;
  const int h = blockIdx.y, q0 = blockIdx.x * 128;
  const int fr = lane & 15, quad = lane >> 4;

  // Q B-fragments (direct from global)
  bf16x8 bq[2][2];
  #pragma unroll
  for (int qf = 0; qf < 2; ++qf)
    #pragma unroll
    for (int ks = 0; ks < 2; ++ks)
      bq[qf][ks] = *(const bf16x8*)&Q[(size_t)(q0 + w * 32 + qf * 16 + fr) * HID
                                      + h * 64 + ks * 32 + quad * 8];

  const int sr = lane >> 3;
  const int sc = ((lane & 7) - sr) & 7;
  const bf16* gk = K  + (size_t)(w * 16 + sr) * HID + h * 64 + sc * 8;
  const bf16* gv = Vt + (size_t)(h * 64 + w * 16 + sr) * SEQ + sc * 8;

  #pragma unroll
  for (int j = 0; j < 2; ++j) {
    gll16(gk + (size_t)(j * 8) * HID, &Ks[0][(w * 16 + j * 8) * 64]);
    gll16(gv + (size_t)(j * 8) * SEQ, &Vs[0][(w * 16 + j * 8) * 64]);
  }

  f32x4 accN[2][4] = {};
  f32x4 accO[2][4] = {};
  float m_i[2] = {-3e38f, -3e38f}, l_i[2] = {0.f, 0.f}, den[2] = {0.f, 0.f};

  __syncthreads();

  for (int kk = 0; kk < 64; ++kk) {
    const int buf = kk & 1;
    if (kk < 63) {
      const size_t key0n = (size_t)(kk + 1) * 64;
      #pragma unroll
      for (int j = 0; j < 2; ++j) {
        gll16(gk + (key0n + j * 8) * HID, &Ks[buf ^ 1][(w * 16 + j * 8) * 64]);
        gll16(gv + key0n + (size_t)(j * 8) * SEQ,
              &Vs[buf ^ 1][(w * 16 + j * 8) * 64]);
      }
    }

    // K fragments (shared across both q-fragments)
    bf16x8 ak[4][2];
    #pragma unroll
    for (int mt = 0; mt < 4; ++mt)
      #pragma unroll
      for (int ks = 0; ks < 2; ++ks)
        ak[mt][ks] = *(const bf16x8*)&Ks[buf][(mt * 16 + fr) * 64 +
                                             ((ks * 4 + quad + fr) & 7) * 8];

    #pragma unroll
    for (int qf = 0; qf < 2; ++qf) {
      f32x4 s[4];
      #pragma unroll
      for (int mt = 0; mt < 4; ++mt) {
        f32x4 z = {};
        z = __builtin_amdgcn_mfma_f32_16x16x32_bf16(ak[mt][0], bq[qf][0], z, 0, 0, 0);
        z = __builtin_amdgcn_mfma_f32_16x16x32_bf16(ak[mt][1], bq[qf][1], z, 0, 0, 0);
        s[mt] = z;
      }
      float mx = -3e38f;
      #pragma unroll
      for (int mt = 0; mt < 4; ++mt)
        #pragma unroll
        for (int r = 0; r < 4; ++r) mx = fmaxf(mx, s[mt][r]);
      mx = fmaxf(mx, __shfl_xor(mx, 16));
      mx = fmaxf(mx, __shfl_xor(mx, 32));
      const float mnew = fmaxf(m_i[qf], mx);
      const float alpha = __expf(m_i[qf] - mnew);
      m_i[qf] = mnew;
      float sum = 0.f;
      const int prow = (qf * 16 + fr) * 64;
      #pragma unroll
      for (int mt = 0; mt < 4; ++mt) {
        float p0 = __expf(s[mt][0] - mnew);
        float p1 = __expf(s[mt][1] - mnew);
        float p2 = __expf(s[mt][2] - mnew);
        float p3 = __expf(s[mt][3] - mnew);
        sum += (p0 + p1) + (p2 + p3);
        bf16x4 pv = {(bf16)p0, (bf16)p1, (bf16)p2, (bf16)p3};
        *(bf16x4*)&Ps[w][prow + ((mt * 2 + (quad >> 1) + fr) & 7) * 8 +
                         (quad & 1) * 4] = pv;
      }
      sum += __shfl_xor(sum, 16);
      sum += __shfl_xor(sum, 32);
      l_i[qf] = l_i[qf] * alpha + sum;
      #pragma unroll
      for (int dt = 0; dt < 4; ++dt) accO[qf][dt] *= alpha;
    }

    // O^T += V^T . P^T
    #pragma unroll
    for (int ks = 0; ks < 2; ++ks) {
      bf16x8 bp0 = *(const bf16x8*)&Ps[w][fr * 64 +
                                          ((ks * 4 + quad + fr) & 7) * 8];
      bf16x8 bp1 = *(const bf16x8*)&Ps[w][(16 + fr) * 64 +
                                          ((ks * 4 + quad + fr) & 7) * 8];
      #pragma unroll
      for (int dt = 0; dt < 4; ++dt) {
        bf16x8 av = *(const bf16x8*)&Vs[buf][(dt * 16 + fr) * 64 +
                                            ((ks * 4 + quad + fr) & 7) * 8];
        accO[0][dt] = __builtin_amdgcn_mfma_f32_16x16x32_bf16(av, bp0, accO[0][dt], 0, 0, 0);
        accO[1][dt] = __builtin_amdgcn_mfma_f32_16x16x32_bf16(av, bp1, accO[1][dt], 0, 0, 0);
      }
    }

    if ((kk & 15) == 15) {   // end of 1024-key block: fold, reset local state
      #pragma unroll
      for (int qf = 0; qf < 2; ++qf) {
        #pragma unroll
        for (int dt = 0; dt < 4; ++dt) {
          #pragma unroll
          for (int r = 0; r < 4; ++r) accN[qf][dt][r] += accO[qf][dt][r];
          accO[qf][dt] = (f32x4){0.f, 0.f, 0.f, 0.f};
        }
        den[qf] += l_i[qf];
        l_i[qf] = 0.f;
        m_i[qf] = -3e38f;
      }
    }
    __syncthreads();
  }

  #pragma unroll
  for (int qf = 0; qf < 2; ++qf) {
    const float inv = 1.0f / den[qf];
    const size_t orow = (size_t)(q0 + w * 32 + qf * 16 + fr) * HID + h * 64;
    #pragma unroll
    for (int dt = 0; dt < 4; ++dt) {
      bf16x4 ov = {(bf16)(accN[qf][dt][0] * inv), (bf16)(accN[qf][dt][1] * inv),
                   (bf16)(accN[qf][dt][2] * inv), (bf16)(accN[qf][dt][3] * inv)};
      *(bf16x4*)&O[orow + dt * 16 + quad * 4] = ov;
    }
  }
}

extern "C" void kernel_launch(void* const* d_in, const int* in_sizes, int n_in,
                              void* d_out, int out_size, void* d_ws, size_t ws_size,
                              hipStream_t stream)
{
  const float* X  = (const float*)d_in[0];
  const float* Wq = (const float*)d_in[1];
  const float* Wk = (const float*)d_in[2];
  const float* Wv = (const float*)d_in[3];
  const float* Wo = (const float*)d_in[4];
  float* out = (float*)d_out;

  const size_t MB = 1024 * 1024;
  bf16* Xb  = (bf16*)d_ws;                       // 8 MB
  bf16* Wt  = (bf16*)((char*)d_ws + 8  * MB);    // 4 x 2 MB
  bf16* Qg  = (bf16*)((char*)d_ws + 16 * MB);    // 8 MB
  bf16* Kg  = (bf16*)((char*)d_ws + 24 * MB);    // 8 MB
  bf16* Vtg = (bf16*)((char*)d_ws + 32 * MB);    // 8 MB, [hid][seq]
  bf16* Og  = (bf16*)((char*)d_ws + 40 * MB);    // 8 MB

  prep_kernel<<<dim3(256, 1, 5), 256, 0, stream>>>(X, Wq, Wk, Wv, Wo, Xb, Wt);
  qkv_gemm<<<dim3(HID / 128, SEQ / 128, 3), 256, 0, stream>>>(Xb, Wt, Qg, Kg, Vtg);
  attn3<<<dim3(SEQ / 128, NHEADS), 256, 0, stream>>>(Qg, Kg, Vtg, Og);
  oproj_gemm<<<dim3(HID / 128, SEQ / 128), 256, 0, stream>>>(
      Og, Wt + (size_t)3 * HID * HID, out);
}